// Round 1
// 181.673 us; speedup vs baseline: 1.0130x; 1.0130x over previous
//
#include <hip/hip_runtime.h>

typedef unsigned short u16;
typedef unsigned int   u32;

#define B_ 2
#define C_ 128
#define T_ 512
#define F_ 64
#define H_ 32
#define D_ 32

// ---- d_out scratch (float offsets): xm1/xf1 fp32 intermediates live in d_out ----
#define XM1_OUT 0u
#define XF1_OUT 2097152u

// ---- d_ws layout (float offsets) ----
#define CORR_OFF 0u          // padded corr: [b][h][518][34]; halo handled in k3 stager
#define WQ_OFF   1127168u    // softmax weights [b][512][32]

// async global->LDS, 16B per lane. LDS dest is wave-uniform base + lane*16;
// global src is per-lane.
__device__ __forceinline__ void gl_lds16(const float* g, float* l){
  __builtin_amdgcn_global_load_lds((const __attribute__((address_space(1))) void*)g,
                                   (__attribute__((address_space(3))) void*)l, 16, 0, 0);
}

// ---------------- K1: projections xm1 = W^T@X + b ----------------
// R5: cooperative LDS staging + 2-phase double buffer.
// Old version: per-thread strided loads; compiler rolled the xv[16] batch to
// ~4 regs (VGPR_Count=40 < acc32+xv16) -> 128 serialized ~800cy latencies =
// 44us at VALUBusy 15%. Now: chunk of 32 c-rows x 256 m staged block-wide via
// global_load_lds (1KB/wave-instr), next chunk's loads issued before current
// chunk's 1024 FMAs, __syncthreads drains vmcnt after compute has covered the
// latency. LDS compute reads are stride-1 per lane (2-way alias = free).
__global__ __launch_bounds__(256) void k1_proj(const float* __restrict__ xm, const float* __restrict__ xf,
                                               const float* __restrict__ w1, const float* __restrict__ b1,
                                               const float* __restrict__ w2, const float* __restrict__ b2,
                                               float* __restrict__ xm1, float* __restrict__ xf1){
  int blk  = blockIdx.x;
  int mblk = blk & 127;
  int bt   = blk >> 7;           // 0..3
  int b    = bt >> 1, sel = bt & 1;
  int m0   = mblk * 256;
  int tid  = threadIdx.x;
  int wave = tid >> 6, lane = tid & 63;

  const float* X    = (sel ? xf : xm) + (size_t)b * (C_*T_*F_) + m0;
  const float* W    = sel ? w2 : w1;
  const float* bias = sel ? b2 : b1;

  __shared__ float ls[2][32*256];   // 2 x 32KB double buffer

  // Stage chunk starting at c-row c0 into ls[buf]: wave w stages rows 8w..8w+7.
  // Dest &ls[buf][r*256] is wave-uniform; HW adds lane*16B -> linear row.
  // Src X + (c0+r)*T*F + lane*4 floats: 64 lanes x 16B = the full 256-float row.
#define K1_STAGE(buf, c0) do {                                            \
    _Pragma("unroll")                                                     \
    for (int i_ = 0; i_ < 8; i_++){                                       \
      int r_ = (wave << 3) + i_;                                          \
      gl_lds16(X + (size_t)((c0) + r_) * (T_*F_) + (lane << 2),           \
               &ls[buf][r_ * 256]);                                       \
    }                                                                     \
  } while (0)

  float acc[H_];
#pragma unroll
  for (int h = 0; h < H_; h++) acc[h] = 0.f;

  K1_STAGE(0, 0);
  __syncthreads();               // vmcnt(0) drain + barrier: buf0 ready

  int cur = 0;
  for (int k = 0; k < 4; k++){
    if (k < 3) K1_STAGE(cur ^ 1, 32*(k+1));   // issue next chunk's loads first
    int c0 = 32*k;
#pragma unroll 4
    for (int u = 0; u < 32; u++){
      float x = ls[cur][u*256 + tid];
      const float* Wr = W + (size_t)(c0 + u) * H_;   // wave-uniform -> s_load, K$
#pragma unroll
      for (int h = 0; h < H_; h++) acc[h] = fmaf(x, Wr[h], acc[h]);
    }
    __syncthreads();             // drains next-chunk vmcnt (issued ~2048cy ago) + barrier
    cur ^= 1;
  }

  float* O = (sel ? xf1 : xm1) + (size_t)b * (H_*T_*F_) + m0 + tid;
#pragma unroll
  for (int h = 0; h < H_; h++) O[(size_t)h * (T_*F_)] = acc[h] + bias[h];
#undef K1_STAGE
}

// ---------------- K2: corr[b,h,t,d] = sum_f xm1[b,h,t,f] * xf1[b,h,t+d-31,f] ----------------
__global__ __launch_bounds__(256) void k2_corr(const float* __restrict__ xm1, const float* __restrict__ xf1,
                                               float* __restrict__ corr_pad){
  int blk = blockIdx.x;
  int tt = blk & 7, h = (blk >> 3) & 31, b = blk >> 8;
  int t0 = tt * 64;
  const float* A  = xm1 + ((size_t)(b*H_ + h)) * (T_*F_);
  const float* Bm = xf1 + ((size_t)(b*H_ + h)) * (T_*F_);

  __shared__ float Al[64*68];
  __shared__ float Bl[95*68];
  int tid = threadIdx.x;

  for (int idx = tid; idx < 64*16; idx += 256){
    int r = idx >> 4, q = idx & 15;
    *(float4*)(Al + r*68 + q*4) = *(const float4*)(A + (size_t)(t0 + r)*F_ + q*4);
  }
  for (int idx = tid; idx < 95*16; idx += 256){
    int r = idx >> 4, q = idx & 15;
    int gr = t0 - 31 + r;
    float4 v = make_float4(0.f,0.f,0.f,0.f);
    if (gr >= 0) v = *(const float4*)(Bm + (size_t)gr*F_ + q*4);
    *(float4*)(Bl + r*68 + q*4) = v;
  }
  __syncthreads();

  int tl = tid >> 2, dg = tid & 3;
  float acc[8];
#pragma unroll
  for (int j = 0; j < 8; j++) acc[j] = 0.f;

  for (int fq = 0; fq < 16; fq++){
    float4 a = *(const float4*)(Al + tl*68 + fq*4);
#pragma unroll
    for (int j = 0; j < 8; j++){
      float4 bv = *(const float4*)(Bl + (tl + dg*8 + j)*68 + fq*4);
      acc[j] += a.x*bv.x + a.y*bv.y + a.z*bv.z + a.w*bv.w;
    }
  }
  float* o = corr_pad + ((size_t)(b*H_ + h))*(518*34) + (size_t)(t0 + tl + 3)*34 + (dg*8 + 1);
#pragma unroll
  for (int j = 0; j < 8; j++) o[j] = acc[j];
}

// ---------------- K3: 5x3 conv over (t,d) summing h + bc, causal mask, softmax over d ----------------
__global__ __launch_bounds__(256) void k3_conv_softmax(const float* __restrict__ corr_pad,
                                                       const float* __restrict__ wc, const float* __restrict__ bc,
                                                       float* __restrict__ wq){
  int b  = blockIdx.x >> 6;
  int t0 = (blockIdx.x & 63) * 8;
  int tid = threadIdx.x;

  __shared__ float ls[32*12*34];   // [h][12 rows t0..t0+11][34 d]
  const float* cp = corr_pad + (size_t)b * (H_*518*34);
  for (int idx = tid; idx < 32*12*34; idx += 256){
    int h = idx / 408, rem = idx - h*408;
    int r = rem / 34, dd = rem - r*34;
    int gr = t0 + r;
    bool halo = (gr < 3) | (gr > 514) | (dd == 0) | (dd == 33);
    ls[idx] = halo ? 0.f : cp[(size_t)h*(518*34) + (size_t)gr*34 + dd];
  }
  __syncthreads();

  int tl = tid >> 5, d = tid & 31;
  int t = t0 + tl;

  float val = bc[0];
  for (int h = 0; h < H_; h++){
    const float* base = ls + h*408 + tl*34 + d;
    const float* wch = wc + h*15;
#pragma unroll
    for (int kh = 0; kh < 5; kh++){
#pragma unroll
      for (int kw = 0; kw < 3; kw++){
        val += base[kh*34 + kw] * wch[kh*3 + kw];
      }
    }
  }
  if (t + d < D_ - 1) val = -1e13f;

  float m = val;
#pragma unroll
  for (int off = 16; off > 0; off >>= 1) m = fmaxf(m, __shfl_xor(m, off));
  float e = __expf(val - m);
  float s = e;
#pragma unroll
  for (int off = 16; off > 0; off >>= 1) s += __shfl_xor(s, off);

  wq[((size_t)b*T_ + t)*D_ + d] = e / s;
}

// ---------------- K4: out[b,c,t,f] = sum_d w[b,t,d] * xf[b,c,t+d-31,f] ----------------
__global__ __launch_bounds__(256) void k4_out(const float* __restrict__ xf, const float* __restrict__ wq,
                                              float* __restrict__ out){
  int blk = blockIdx.x;
  int tt = blk & 7, c = (blk >> 3) & 127, b = blk >> 10;
  int t0 = tt * 64;
  const float* Xf = xf + ((size_t)(b*C_ + c)) * (T_*F_);

  __shared__ float xfl[95*68];
  __shared__ float wl[64*33];
  int tid = threadIdx.x;

  for (int idx = tid; idx < 95*16; idx += 256){
    int r = idx >> 4, q = idx & 15;
    int gr = t0 - 31 + r;
    float4 v = make_float4(0.f,0.f,0.f,0.f);
    if (gr >= 0) v = *(const float4*)(Xf + (size_t)gr*F_ + q*4);
    *(float4*)(xfl + r*68 + q*4) = v;
  }
  for (int idx = tid; idx < 64*8; idx += 256){
    int r = idx >> 3, q = idx & 7;
    float4 v = *(const float4*)(wq + ((size_t)b*T_ + t0 + r)*D_ + q*4);
    wl[r*33 + q*4 + 0] = v.x; wl[r*33 + q*4 + 1] = v.y;
    wl[r*33 + q*4 + 2] = v.z; wl[r*33 + q*4 + 3] = v.w;
  }
  __syncthreads();

  int tg = tid >> 4, q = tid & 15;
  float4 acc[4];
#pragma unroll
  for (int j = 0; j < 4; j++) acc[j] = make_float4(0.f,0.f,0.f,0.f);

#pragma unroll
  for (int rr = 0; rr < 35; rr++){
    float4 xv = *(const float4*)(xfl + (tg*4 + rr)*68 + q*4);
#pragma unroll
    for (int j = 0; j < 4; j++){
      int d = rr - j;
      if (d >= 0 && d < D_){
        float wv = wl[(tg*4 + j)*33 + d];
        acc[j].x += wv * xv.x; acc[j].y += wv * xv.y;
        acc[j].z += wv * xv.z; acc[j].w += wv * xv.w;
      }
    }
  }
#pragma unroll
  for (int j = 0; j < 4; j++){
    int t = t0 + tg*4 + j;
    float* O = out + (((size_t)(b*C_ + c))*T_ + t)*F_ + q*4;
    *(float4*)O = acc[j];
  }
}

extern "C" void kernel_launch(void* const* d_in, const int* in_sizes, int n_in,
                              void* d_out, int out_size, void* d_ws, size_t ws_size,
                              hipStream_t stream) {
  const float* xm = (const float*)d_in[0];
  const float* xf = (const float*)d_in[1];
  const float* w1 = (const float*)d_in[2];
  const float* b1 = (const float*)d_in[3];
  const float* w2 = (const float*)d_in[4];
  const float* b2 = (const float*)d_in[5];
  const float* wc = (const float*)d_in[6];
  const float* bc = (const float*)d_in[7];
  float* ws = (float*)d_ws;

  float* xm1 = (float*)d_out + XM1_OUT;
  float* xf1 = (float*)d_out + XF1_OUT;

  hipLaunchKernelGGL(k1_proj, dim3(512), dim3(256), 0, stream, xm, xf, w1, b1, w2, b2, xm1, xf1);
  hipLaunchKernelGGL(k2_corr, dim3(512), dim3(256), 0, stream, xm1, xf1, ws + CORR_OFF);
  hipLaunchKernelGGL(k3_conv_softmax, dim3(128), dim3(256), 0, stream, ws + CORR_OFF, wc, bc, ws + WQ_OFF);
  hipLaunchKernelGGL(k4_out, dim3(2048), dim3(256), 0, stream, xf, ws + WQ_OFF, (float*)d_out);
}

// Round 2
// 173.815 us; speedup vs baseline: 1.0588x; 1.0452x over previous
//
#include <hip/hip_runtime.h>

typedef unsigned short u16;
typedef unsigned int   u32;

#define B_ 2
#define C_ 128
#define T_ 512
#define F_ 64
#define H_ 32
#define D_ 32

// ---- d_out scratch (float offsets): xm1/xf1 fp32 intermediates live in d_out ----
#define XM1_OUT 0u
#define XF1_OUT 2097152u

// ---- d_ws layout (float offsets) ----
#define CORR_OFF 0u          // padded corr: [b][h][518][34]; halo handled in k3 stager
#define WQ_OFF   1127168u    // softmax weights [b][512][32]

// async global->LDS, 16B per lane. LDS dest is wave-uniform base + lane*16;
// global src is per-lane.
__device__ __forceinline__ void gl_lds16(const float* g, float* l){
  __builtin_amdgcn_global_load_lds((const __attribute__((address_space(1))) void*)g,
                                   (__attribute__((address_space(3))) void*)l, 16, 0, 0);
}

// ---------------- K1: projections xm1 = W^T@X + b ----------------
// R6: DS-only inner loop.
// R5 post-mortem: LDS-staging X didn't move k1 (42us, VALUBusy ~15%) because
// the shared bottleneck was the per-u s_load of W (128B/iter): SGPRs (112)
// can't hold an unrolled batch, and mixing SMEM+DS in lgkmcnt forces
// lgkmcnt(0) drains every iteration (~250cy exposed per u).
// Now: W (16KB) staged to LDS once; thread tile 4m x 8h (wave=hg, lane=mg);
// per c-row: 1x ds_read_b128 (x, per-lane contiguous) + 2x ds_read_b128
// (W, wave-uniform broadcast = conflict-free) + 32 FMA. No SMEM in loop ->
// compiler's fine-grained lgkmcnt(N) pipelining applies.
__global__ __launch_bounds__(256) void k1_proj(const float* __restrict__ xm, const float* __restrict__ xf,
                                               const float* __restrict__ w1, const float* __restrict__ b1,
                                               const float* __restrict__ w2, const float* __restrict__ b2,
                                               float* __restrict__ xm1, float* __restrict__ xf1){
  int blk  = blockIdx.x;
  int mblk = blk & 127;
  int bt   = blk >> 7;           // 0..3
  int b    = bt >> 1, sel = bt & 1;
  int m0   = mblk * 256;
  int tid  = threadIdx.x;
  int wave = tid >> 6, lane = tid & 63;

  const float* X    = (sel ? xf : xm) + (size_t)b * (C_*T_*F_) + m0;
  const float* W    = sel ? w2 : w1;
  const float* bias = sel ? b2 : b1;

  __shared__ float xs[2][32*256];   // 2 x 32KB double buffer of X chunks [c][m]
  __shared__ float wls[C_*H_];      // 16KB: full W [c][h]

  // Stage X chunk starting at c-row c0 into xs[buf]: wave w stages rows 8w..8w+7.
#define K1_STAGE(buf, c0) do {                                            \
    _Pragma("unroll")                                                     \
    for (int i_ = 0; i_ < 8; i_++){                                       \
      int r_ = (wave << 3) + i_;                                          \
      gl_lds16(X + (size_t)((c0) + r_) * (T_*F_) + (lane << 2),           \
               &xs[buf][r_ * 256]);                                       \
    }                                                                     \
  } while (0)

  // Stage full W: 4096 floats = 16 x 1KB wave-instrs, 4 per wave.
#pragma unroll
  for (int i = 0; i < 4; i++){
    int j = wave * 4 + i;
    gl_lds16(W + j * 256 + (lane << 2), wls + j * 256);
  }
  K1_STAGE(0, 0);

  int mg = tid & 63;             // m sub-tile: 4 consecutive floats
  int hg = tid >> 6;             // h sub-tile: 8 consecutive h (constant per wave)

  float4 acc[8];
#pragma unroll
  for (int j = 0; j < 8; j++) acc[j] = make_float4(0.f,0.f,0.f,0.f);

  __syncthreads();               // vmcnt(0) drain + barrier: buf0 + W ready

#define FMA4(A, Wv) do { \
    A.x = fmaf((Wv), xv.x, A.x); A.y = fmaf((Wv), xv.y, A.y); \
    A.z = fmaf((Wv), xv.z, A.z); A.w = fmaf((Wv), xv.w, A.w); } while (0)

  int cur = 0;
  for (int k = 0; k < 4; k++){
    if (k < 3) K1_STAGE(cur ^ 1, 32*(k+1));   // issue next chunk's loads first
    const float* wk = wls + (k*32)*H_ + hg*8;
#pragma unroll 8
    for (int u = 0; u < 32; u++){
      float4 xv = *(const float4*)(&xs[cur][u*256 + (mg << 2)]);
      float4 wa = *(const float4*)(wk + u*H_);
      float4 wb = *(const float4*)(wk + u*H_ + 4);
      FMA4(acc[0], wa.x); FMA4(acc[1], wa.y); FMA4(acc[2], wa.z); FMA4(acc[3], wa.w);
      FMA4(acc[4], wb.x); FMA4(acc[5], wb.y); FMA4(acc[6], wb.z); FMA4(acc[7], wb.w);
    }
    __syncthreads();             // drains next-chunk vmcnt (issued ~2048cy ago) + barrier
    cur ^= 1;
  }

  float* O = (sel ? xf1 : xm1) + (size_t)b * (H_*T_*F_) + m0 + (mg << 2);
#pragma unroll
  for (int j = 0; j < 8; j++){
    int h = hg*8 + j;
    float bv = bias[h];
    float4 o = make_float4(acc[j].x + bv, acc[j].y + bv, acc[j].z + bv, acc[j].w + bv);
    *(float4*)(O + (size_t)h * (T_*F_)) = o;
  }
#undef K1_STAGE
#undef FMA4
}

// ---------------- K2: corr[b,h,t,d] = sum_f xm1[b,h,t,f] * xf1[b,h,t+d-31,f] ----------------
__global__ __launch_bounds__(256) void k2_corr(const float* __restrict__ xm1, const float* __restrict__ xf1,
                                               float* __restrict__ corr_pad){
  int blk = blockIdx.x;
  int tt = blk & 7, h = (blk >> 3) & 31, b = blk >> 8;
  int t0 = tt * 64;
  const float* A  = xm1 + ((size_t)(b*H_ + h)) * (T_*F_);
  const float* Bm = xf1 + ((size_t)(b*H_ + h)) * (T_*F_);

  __shared__ float Al[64*68];
  __shared__ float Bl[95*68];
  int tid = threadIdx.x;

  for (int idx = tid; idx < 64*16; idx += 256){
    int r = idx >> 4, q = idx & 15;
    *(float4*)(Al + r*68 + q*4) = *(const float4*)(A + (size_t)(t0 + r)*F_ + q*4);
  }
  for (int idx = tid; idx < 95*16; idx += 256){
    int r = idx >> 4, q = idx & 15;
    int gr = t0 - 31 + r;
    float4 v = make_float4(0.f,0.f,0.f,0.f);
    if (gr >= 0) v = *(const float4*)(Bm + (size_t)gr*F_ + q*4);
    *(float4*)(Bl + r*68 + q*4) = v;
  }
  __syncthreads();

  int tl = tid >> 2, dg = tid & 3;
  float acc[8];
#pragma unroll
  for (int j = 0; j < 8; j++) acc[j] = 0.f;

  for (int fq = 0; fq < 16; fq++){
    float4 a = *(const float4*)(Al + tl*68 + fq*4);
#pragma unroll
    for (int j = 0; j < 8; j++){
      float4 bv = *(const float4*)(Bl + (tl + dg*8 + j)*68 + fq*4);
      acc[j] += a.x*bv.x + a.y*bv.y + a.z*bv.z + a.w*bv.w;
    }
  }
  float* o = corr_pad + ((size_t)(b*H_ + h))*(518*34) + (size_t)(t0 + tl + 3)*34 + (dg*8 + 1);
#pragma unroll
  for (int j = 0; j < 8; j++) o[j] = acc[j];
}

// ---------------- K3: 5x3 conv over (t,d) summing h + bc, causal mask, softmax over d ----------------
__global__ __launch_bounds__(256) void k3_conv_softmax(const float* __restrict__ corr_pad,
                                                       const float* __restrict__ wc, const float* __restrict__ bc,
                                                       float* __restrict__ wq){
  int b  = blockIdx.x >> 6;
  int t0 = (blockIdx.x & 63) * 8;
  int tid = threadIdx.x;

  __shared__ float ls[32*12*34];   // [h][12 rows t0..t0+11][34 d]
  const float* cp = corr_pad + (size_t)b * (H_*518*34);
  for (int idx = tid; idx < 32*12*34; idx += 256){
    int h = idx / 408, rem = idx - h*408;
    int r = rem / 34, dd = rem - r*34;
    int gr = t0 + r;
    bool halo = (gr < 3) | (gr > 514) | (dd == 0) | (dd == 33);
    ls[idx] = halo ? 0.f : cp[(size_t)h*(518*34) + (size_t)gr*34 + dd];
  }
  __syncthreads();

  int tl = tid >> 5, d = tid & 31;
  int t = t0 + tl;

  float val = bc[0];
  for (int h = 0; h < H_; h++){
    const float* base = ls + h*408 + tl*34 + d;
    const float* wch = wc + h*15;
#pragma unroll
    for (int kh = 0; kh < 5; kh++){
#pragma unroll
      for (int kw = 0; kw < 3; kw++){
        val += base[kh*34 + kw] * wch[kh*3 + kw];
      }
    }
  }
  if (t + d < D_ - 1) val = -1e13f;

  float m = val;
#pragma unroll
  for (int off = 16; off > 0; off >>= 1) m = fmaxf(m, __shfl_xor(m, off));
  float e = __expf(val - m);
  float s = e;
#pragma unroll
  for (int off = 16; off > 0; off >>= 1) s += __shfl_xor(s, off);

  wq[((size_t)b*T_ + t)*D_ + d] = e / s;
}

// ---------------- K4: out[b,c,t,f] = sum_d w[b,t,d] * xf[b,c,t+d-31,f] ----------------
__global__ __launch_bounds__(256) void k4_out(const float* __restrict__ xf, const float* __restrict__ wq,
                                              float* __restrict__ out){
  int blk = blockIdx.x;
  int tt = blk & 7, c = (blk >> 3) & 127, b = blk >> 10;
  int t0 = tt * 64;
  const float* Xf = xf + ((size_t)(b*C_ + c)) * (T_*F_);

  __shared__ float xfl[95*68];
  __shared__ float wl[64*33];
  int tid = threadIdx.x;

  for (int idx = tid; idx < 95*16; idx += 256){
    int r = idx >> 4, q = idx & 15;
    int gr = t0 - 31 + r;
    float4 v = make_float4(0.f,0.f,0.f,0.f);
    if (gr >= 0) v = *(const float4*)(Xf + (size_t)gr*F_ + q*4);
    *(float4*)(xfl + r*68 + q*4) = v;
  }
  for (int idx = tid; idx < 64*8; idx += 256){
    int r = idx >> 3, q = idx & 7;
    float4 v = *(const float4*)(wq + ((size_t)b*T_ + t0 + r)*D_ + q*4);
    wl[r*33 + q*4 + 0] = v.x; wl[r*33 + q*4 + 1] = v.y;
    wl[r*33 + q*4 + 2] = v.z; wl[r*33 + q*4 + 3] = v.w;
  }
  __syncthreads();

  int tg = tid >> 4, q = tid & 15;
  float4 acc[4];
#pragma unroll
  for (int j = 0; j < 4; j++) acc[j] = make_float4(0.f,0.f,0.f,0.f);

#pragma unroll
  for (int rr = 0; rr < 35; rr++){
    float4 xv = *(const float4*)(xfl + (tg*4 + rr)*68 + q*4);
#pragma unroll
    for (int j = 0; j < 4; j++){
      int d = rr - j;
      if (d >= 0 && d < D_){
        float wv = wl[(tg*4 + j)*33 + d];
        acc[j].x += wv * xv.x; acc[j].y += wv * xv.y;
        acc[j].z += wv * xv.z; acc[j].w += wv * xv.w;
      }
    }
  }
#pragma unroll
  for (int j = 0; j < 4; j++){
    int t = t0 + tg*4 + j;
    float* O = out + (((size_t)(b*C_ + c))*T_ + t)*F_ + q*4;
    *(float4*)O = acc[j];
  }
}

extern "C" void kernel_launch(void* const* d_in, const int* in_sizes, int n_in,
                              void* d_out, int out_size, void* d_ws, size_t ws_size,
                              hipStream_t stream) {
  const float* xm = (const float*)d_in[0];
  const float* xf = (const float*)d_in[1];
  const float* w1 = (const float*)d_in[2];
  const float* b1 = (const float*)d_in[3];
  const float* w2 = (const float*)d_in[4];
  const float* b2 = (const float*)d_in[5];
  const float* wc = (const float*)d_in[6];
  const float* bc = (const float*)d_in[7];
  float* ws = (float*)d_ws;

  float* xm1 = (float*)d_out + XM1_OUT;
  float* xf1 = (float*)d_out + XF1_OUT;

  hipLaunchKernelGGL(k1_proj, dim3(512), dim3(256), 0, stream, xm, xf, w1, b1, w2, b2, xm1, xf1);
  hipLaunchKernelGGL(k2_corr, dim3(512), dim3(256), 0, stream, xm1, xf1, ws + CORR_OFF);
  hipLaunchKernelGGL(k3_conv_softmax, dim3(128), dim3(256), 0, stream, ws + CORR_OFF, wc, bc, ws + WQ_OFF);
  hipLaunchKernelGGL(k4_out, dim3(2048), dim3(256), 0, stream, xf, ws + WQ_OFF, (float*)d_out);
}

// Round 3
// 173.071 us; speedup vs baseline: 1.0633x; 1.0043x over previous
//
#include <hip/hip_runtime.h>

typedef unsigned short u16;
typedef unsigned int   u32;

#define B_ 2
#define C_ 128
#define T_ 512
#define F_ 64
#define H_ 32
#define D_ 32

// ---- d_out scratch (float offsets): xm1/xf1 fp32 intermediates live in d_out ----
#define XM1_OUT 0u
#define XF1_OUT 2097152u

// ---- d_ws layout (float offsets) ----
#define CORR_OFF 0u          // padded corr: [b][h][518][34]; halo handled in k3 stager
#define WQ_OFF   1127168u    // softmax weights [b][512][32]

// async global->LDS, 16B per lane. LDS dest is wave-uniform base + lane*16;
// global src is per-lane.
__device__ __forceinline__ void gl_lds16(const float* g, float* l){
  __builtin_amdgcn_global_load_lds((const __attribute__((address_space(1))) void*)g,
                                   (__attribute__((address_space(3))) void*)l, 16, 0, 0);
}

// ---------------- K1: projections xm1 = W^T@X + b ----------------
// R7: CHUNK 32->16. R6's 80KB LDS (2x32KB xs + 16KB W) fit 2 blocks/CU only at
// exactly 160KB -- occupancy-fragile (possibly 1 block/CU = 1 wave/SIMD, all
// staging drains exposed). Now 2x16KB + 16KB = 48KB -> 3 blocks/CU guaranteed,
// 8 chunks double-buffered, DS-only inner loop (R6's W-in-LDS kept).
__global__ __launch_bounds__(256) void k1_proj(const float* __restrict__ xm, const float* __restrict__ xf,
                                               const float* __restrict__ w1, const float* __restrict__ b1,
                                               const float* __restrict__ w2, const float* __restrict__ b2,
                                               float* __restrict__ xm1, float* __restrict__ xf1){
  int blk  = blockIdx.x;
  int mblk = blk & 127;
  int bt   = blk >> 7;           // 0..3
  int b    = bt >> 1, sel = bt & 1;
  int m0   = mblk * 256;
  int tid  = threadIdx.x;
  int wave = tid >> 6, lane = tid & 63;

  const float* X    = (sel ? xf : xm) + (size_t)b * (C_*T_*F_) + m0;
  const float* W    = sel ? w2 : w1;
  const float* bias = sel ? b2 : b1;

  __shared__ float xs[2][16*256];   // 2 x 16KB double buffer of X chunks [c][m]
  __shared__ float wls[C_*H_];      // 16KB: full W [c][h]

  // Stage X chunk (16 c-rows) starting at c0 into xs[buf]: wave w stages rows 4w..4w+3.
#define K1_STAGE(buf, c0) do {                                            \
    _Pragma("unroll")                                                     \
    for (int i_ = 0; i_ < 4; i_++){                                       \
      int r_ = (wave << 2) + i_;                                          \
      gl_lds16(X + (size_t)((c0) + r_) * (T_*F_) + (lane << 2),           \
               &xs[buf][r_ * 256]);                                       \
    }                                                                     \
  } while (0)

  // Stage full W: 4096 floats = 16 x 1KB wave-instrs, 4 per wave.
#pragma unroll
  for (int i = 0; i < 4; i++){
    int j = wave * 4 + i;
    gl_lds16(W + j * 256 + (lane << 2), wls + j * 256);
  }
  K1_STAGE(0, 0);

  int mg = tid & 63;             // m sub-tile: 4 consecutive floats
  int hg = tid >> 6;             // h sub-tile: 8 consecutive h (constant per wave)

  float4 acc[8];
#pragma unroll
  for (int j = 0; j < 8; j++) acc[j] = make_float4(0.f,0.f,0.f,0.f);

  __syncthreads();               // vmcnt(0) drain + barrier: buf0 + W ready

#define FMA4(A, Wv) do { \
    A.x = fmaf((Wv), xv.x, A.x); A.y = fmaf((Wv), xv.y, A.y); \
    A.z = fmaf((Wv), xv.z, A.z); A.w = fmaf((Wv), xv.w, A.w); } while (0)

  int cur = 0;
  for (int k = 0; k < 8; k++){
    if (k < 7) K1_STAGE(cur ^ 1, 16*(k+1));   // issue next chunk's loads first
    const float* wk = wls + (k*16)*H_ + hg*8;
#pragma unroll
    for (int u = 0; u < 16; u++){
      float4 xv = *(const float4*)(&xs[cur][u*256 + (mg << 2)]);
      float4 wa = *(const float4*)(wk + u*H_);
      float4 wb = *(const float4*)(wk + u*H_ + 4);
      FMA4(acc[0], wa.x); FMA4(acc[1], wa.y); FMA4(acc[2], wa.z); FMA4(acc[3], wa.w);
      FMA4(acc[4], wb.x); FMA4(acc[5], wb.y); FMA4(acc[6], wb.z); FMA4(acc[7], wb.w);
    }
    __syncthreads();             // drains next-chunk vmcnt (issued ~1024cy ago) + barrier
    cur ^= 1;
  }

  float* O = (sel ? xf1 : xm1) + (size_t)b * (H_*T_*F_) + m0 + (mg << 2);
#pragma unroll
  for (int j = 0; j < 8; j++){
    int h = hg*8 + j;
    float bv = bias[h];
    float4 o = make_float4(acc[j].x + bv, acc[j].y + bv, acc[j].z + bv, acc[j].w + bv);
    *(float4*)(O + (size_t)h * (T_*F_)) = o;
  }
#undef K1_STAGE
#undef FMA4
}

// ---------------- K2: corr[b,h,t,d] = sum_f xm1[b,h,t,f] * xf1[b,h,t+d-31,f] ----------------
// R7: XOR-swizzle Bl. Inner-loop Bl rows are tl + dg*8 + j: rows differing by 8
// at stride 68 floats hit the same bank ((4r) mod 32 has period 8) -> ~5-way
// conflict on 8 of 9 reads/fq. Swizzle the float4 slot within the row by
// ((r>>3)&7)<<2 (bijective; same formula on write and read) -> rows r,r+8,r+16,
// r+24,r+32 land on distinct banks.
#define BSW(r) ((((r) >> 3) & 7) << 2)

__global__ __launch_bounds__(256) void k2_corr(const float* __restrict__ xm1, const float* __restrict__ xf1,
                                               float* __restrict__ corr_pad){
  int blk = blockIdx.x;
  int tt = blk & 7, h = (blk >> 3) & 31, b = blk >> 8;
  int t0 = tt * 64;
  const float* A  = xm1 + ((size_t)(b*H_ + h)) * (T_*F_);
  const float* Bm = xf1 + ((size_t)(b*H_ + h)) * (T_*F_);

  __shared__ float Al[64*68];
  __shared__ float Bl[95*68];
  int tid = threadIdx.x;

  for (int idx = tid; idx < 64*16; idx += 256){
    int r = idx >> 4, q = idx & 15;
    *(float4*)(Al + r*68 + q*4) = *(const float4*)(A + (size_t)(t0 + r)*F_ + q*4);
  }
  for (int idx = tid; idx < 95*16; idx += 256){
    int r = idx >> 4, q = idx & 15;
    int gr = t0 - 31 + r;
    float4 v = make_float4(0.f,0.f,0.f,0.f);
    if (gr >= 0) v = *(const float4*)(Bm + (size_t)gr*F_ + q*4);
    *(float4*)(Bl + r*68 + ((q*4) ^ BSW(r))) = v;
  }
  __syncthreads();

  int tl = tid >> 2, dg = tid & 3;
  float acc[8];
#pragma unroll
  for (int j = 0; j < 8; j++) acc[j] = 0.f;

  for (int fq = 0; fq < 16; fq++){
    float4 a = *(const float4*)(Al + tl*68 + fq*4);
#pragma unroll
    for (int j = 0; j < 8; j++){
      int rbj = tl + dg*8 + j;
      float4 bv = *(const float4*)(Bl + rbj*68 + ((fq*4) ^ BSW(rbj)));
      acc[j] += a.x*bv.x + a.y*bv.y + a.z*bv.z + a.w*bv.w;
    }
  }
  float* o = corr_pad + ((size_t)(b*H_ + h))*(518*34) + (size_t)(t0 + tl + 3)*34 + (dg*8 + 1);
#pragma unroll
  for (int j = 0; j < 8; j++) o[j] = acc[j];
}

// ---------------- K3: 5x3 conv over (t,d) summing h + bc, causal mask, softmax over d ----------------
__global__ __launch_bounds__(256) void k3_conv_softmax(const float* __restrict__ corr_pad,
                                                       const float* __restrict__ wc, const float* __restrict__ bc,
                                                       float* __restrict__ wq){
  int b  = blockIdx.x >> 6;
  int t0 = (blockIdx.x & 63) * 8;
  int tid = threadIdx.x;

  __shared__ float ls[32*12*34];   // [h][12 rows t0..t0+11][34 d]
  const float* cp = corr_pad + (size_t)b * (H_*518*34);
  for (int idx = tid; idx < 32*12*34; idx += 256){
    int h = idx / 408, rem = idx - h*408;
    int r = rem / 34, dd = rem - r*34;
    int gr = t0 + r;
    bool halo = (gr < 3) | (gr > 514) | (dd == 0) | (dd == 33);
    ls[idx] = halo ? 0.f : cp[(size_t)h*(518*34) + (size_t)gr*34 + dd];
  }
  __syncthreads();

  int tl = tid >> 5, d = tid & 31;
  int t = t0 + tl;

  float val = bc[0];
  for (int h = 0; h < H_; h++){
    const float* base = ls + h*408 + tl*34 + d;
    const float* wch = wc + h*15;
#pragma unroll
    for (int kh = 0; kh < 5; kh++){
#pragma unroll
      for (int kw = 0; kw < 3; kw++){
        val += base[kh*34 + kw] * wch[kh*3 + kw];
      }
    }
  }
  if (t + d < D_ - 1) val = -1e13f;

  float m = val;
#pragma unroll
  for (int off = 16; off > 0; off >>= 1) m = fmaxf(m, __shfl_xor(m, off));
  float e = __expf(val - m);
  float s = e;
#pragma unroll
  for (int off = 16; off > 0; off >>= 1) s += __shfl_xor(s, off);

  wq[((size_t)b*T_ + t)*D_ + d] = e / s;
}

// ---------------- K4: out[b,c,t,f] = sum_d w[b,t,d] * xf[b,c,t+d-31,f] ----------------
__global__ __launch_bounds__(256) void k4_out(const float* __restrict__ xf, const float* __restrict__ wq,
                                              float* __restrict__ out){
  int blk = blockIdx.x;
  int tt = blk & 7, c = (blk >> 3) & 127, b = blk >> 10;
  int t0 = tt * 64;
  const float* Xf = xf + ((size_t)(b*C_ + c)) * (T_*F_);

  __shared__ float xfl[95*68];
  __shared__ float wl[64*33];
  int tid = threadIdx.x;

  for (int idx = tid; idx < 95*16; idx += 256){
    int r = idx >> 4, q = idx & 15;
    int gr = t0 - 31 + r;
    float4 v = make_float4(0.f,0.f,0.f,0.f);
    if (gr >= 0) v = *(const float4*)(Xf + (size_t)gr*F_ + q*4);
    *(float4*)(xfl + r*68 + q*4) = v;
  }
  for (int idx = tid; idx < 64*8; idx += 256){
    int r = idx >> 3, q = idx & 7;
    float4 v = *(const float4*)(wq + ((size_t)b*T_ + t0 + r)*D_ + q*4);
    wl[r*33 + q*4 + 0] = v.x; wl[r*33 + q*4 + 1] = v.y;
    wl[r*33 + q*4 + 2] = v.z; wl[r*33 + q*4 + 3] = v.w;
  }
  __syncthreads();

  int tg = tid >> 4, q = tid & 15;
  float4 acc[4];
#pragma unroll
  for (int j = 0; j < 4; j++) acc[j] = make_float4(0.f,0.f,0.f,0.f);

#pragma unroll
  for (int rr = 0; rr < 35; rr++){
    float4 xv = *(const float4*)(xfl + (tg*4 + rr)*68 + q*4);
#pragma unroll
    for (int j = 0; j < 4; j++){
      int d = rr - j;
      if (d >= 0 && d < D_){
        float wv = wl[(tg*4 + j)*33 + d];
        acc[j].x += wv * xv.x; acc[j].y += wv * xv.y;
        acc[j].z += wv * xv.z; acc[j].w += wv * xv.w;
      }
    }
  }
#pragma unroll
  for (int j = 0; j < 4; j++){
    int t = t0 + tg*4 + j;
    float* O = out + (((size_t)(b*C_ + c))*T_ + t)*F_ + q*4;
    *(float4*)O = acc[j];
  }
}

extern "C" void kernel_launch(void* const* d_in, const int* in_sizes, int n_in,
                              void* d_out, int out_size, void* d_ws, size_t ws_size,
                              hipStream_t stream) {
  const float* xm = (const float*)d_in[0];
  const float* xf = (const float*)d_in[1];
  const float* w1 = (const float*)d_in[2];
  const float* b1 = (const float*)d_in[3];
  const float* w2 = (const float*)d_in[4];
  const float* b2 = (const float*)d_in[5];
  const float* wc = (const float*)d_in[6];
  const float* bc = (const float*)d_in[7];
  float* ws = (float*)d_ws;

  float* xm1 = (float*)d_out + XM1_OUT;
  float* xf1 = (float*)d_out + XF1_OUT;

  hipLaunchKernelGGL(k1_proj, dim3(512), dim3(256), 0, stream, xm, xf, w1, b1, w2, b2, xm1, xf1);
  hipLaunchKernelGGL(k2_corr, dim3(512), dim3(256), 0, stream, xm1, xf1, ws + CORR_OFF);
  hipLaunchKernelGGL(k3_conv_softmax, dim3(128), dim3(256), 0, stream, ws + CORR_OFF, wc, bc, ws + WQ_OFF);
  hipLaunchKernelGGL(k4_out, dim3(2048), dim3(256), 0, stream, xf, ws + WQ_OFF, (float*)d_out);
}